// Round 2
// baseline (377.460 us; speedup 1.0000x reference)
//
#include <hip/hip_runtime.h>
#include <hip/hip_bf16.h>
#include <math.h>

// LSTM cell fused kernel, MI355X gfx950.
// B=65536, I=128, H=256, O=256, K=I+H=384.
// out = [log_softmax(combined@w_i2o.T+b_i2o) (B*256), new_hidden (B*256)]
//
// R2: explicit B double-buffer pipeline + XOR-swizzled LDS A-tile (no pad).

typedef __attribute__((ext_vector_type(8))) short bf16x8;   // 8 bf16 = 4 VGPRs
typedef __attribute__((ext_vector_type(4))) float f32x4;

#define BM   64     // rows per block
#define NW1  393216 // 1024*384
#define NW2  98304  // 256*384

__device__ __forceinline__ unsigned short f2bf(float f) {
    union { __hip_bfloat16 h; unsigned short u; } cv;
    cv.h = __float2bfloat16(f);
    return cv.u;
}
__device__ __forceinline__ float bf2f(unsigned short u) {
    union { __hip_bfloat16 h; unsigned short u; } cv;
    cv.u = u;
    return __bfloat162float(cv.h);
}
__device__ __forceinline__ float fsigmoid(float x) {
    return 1.0f / (1.0f + __expf(-x));
}
__device__ __forceinline__ float ftanh(float x) {
    return 1.0f - 2.0f / (__expf(2.0f * x) + 1.0f);
}
__device__ __forceinline__ bf16x8 pack8(float4 v0, float4 v1) {
    bf16x8 r;
    r[0] = (short)f2bf(v0.x); r[1] = (short)f2bf(v0.y);
    r[2] = (short)f2bf(v0.z); r[3] = (short)f2bf(v0.w);
    r[4] = (short)f2bf(v1.x); r[5] = (short)f2bf(v1.y);
    r[6] = (short)f2bf(v1.z); r[7] = (short)f2bf(v1.w);
    return r;
}

// Convert fp32 weights -> bf16 into workspace. Runs every launch (ws is re-poisoned).
__global__ void conv_w(const float* __restrict__ w1, const float* __restrict__ w2,
                       unsigned short* __restrict__ wb) {
    int idx = blockIdx.x * 256 + threadIdx.x;   // per-float4; total (NW1+NW2)/4 = 122880
    const int n1 = NW1 / 4;
    float4 v;
    if (idx < n1) v = ((const float4*)w1)[idx];
    else          v = ((const float4*)w2)[idx - n1];
    ushort4 u;
    u.x = f2bf(v.x); u.y = f2bf(v.y); u.z = f2bf(v.z); u.w = f2bf(v.w);
    ((ushort4*)wb)[idx] = u;
}

// LDS layout: row stride 768 B (384 bf16, NO pad). 16B granule g of row r is
// stored at granule (g ^ (r & 7)). Row starts all hit bank 0, but the XOR
// spreads the 16 rows a quad reads over 8 granule-banks (2-way = free, m136).
__device__ __forceinline__ int lds_off(int row, int g) {
    return row * 768 + ((g ^ (row & 7)) << 4);
}

__launch_bounds__(256, 3)
__global__ void lstm_fused(const float* __restrict__ input,    // [B,128]
                           const float* __restrict__ hidden,   // [B,256]
                           const unsigned short* __restrict__ w1b, // bf16 [1024][384]
                           const unsigned short* __restrict__ w2b, // bf16 [256][384]
                           const float* __restrict__ b1,       // [1024]
                           const float* __restrict__ b2,       // [256]
                           float* __restrict__ out_ls,         // [B,256]
                           float* __restrict__ out_nh)         // [B,256]
{
    __shared__ __align__(16) unsigned short Ash[BM * 384];   // 49152 B
    __shared__ float red_m[4][BM];
    __shared__ float red_s[4][BM];
    char* Ab = (char*)Ash;

    const int tid  = threadIdx.x;
    const int wave = tid >> 6;
    const int lane = tid & 63;
    const int l15  = lane & 15;
    const int quad = lane >> 4;
    const int rx   = l15 & 7;
    const size_t r0 = (size_t)blockIdx.x * BM;

    // ---- stage combined [64 x 384] fp32 -> bf16 LDS (16B granules, swizzled) ----
    #pragma unroll
    for (int it = 0; it < 12; ++it) {
        int idx = it * 256 + tid;          // 0..3071 granules
        int row = idx / 48, g = idx % 48;
        const float* src = (g < 16) ? (input  + (r0 + row) * 128 + g * 8)
                                    : (hidden + (r0 + row) * 256 + (g - 16) * 8);
        float4 v0 = ((const float4*)src)[0];
        float4 v1 = ((const float4*)src)[1];
        *(bf16x8*)(Ab + lds_off(row, g)) = pack8(v0, v1);
    }
    __syncthreads();

    const int abase = l15 * 768;           // row = l15 + mt*16 -> +mt*12288

    for (int phase = 0; phase < 5; ++phase) {
        f32x4 acc[4][4];
        #pragma unroll
        for (int i = 0; i < 4; ++i)
            #pragma unroll
            for (int j = 0; j < 4; ++j)
                acc[i][j] = (f32x4){0.f, 0.f, 0.f, 0.f};

        // B-operand per-lane row pointers (lane holds W[n = col][k = quad*8+j])
        const unsigned short* bp[4];
        if (phase < 4) {
            int j0 = phase * 64 + wave * 16;
            #pragma unroll
            for (int q = 0; q < 4; ++q)
                bp[q] = w1b + (size_t)(q * 256 + j0 + l15) * 384 + quad * 8;
        } else {
            #pragma unroll
            for (int nt = 0; nt < 4; ++nt)
                bp[nt] = w2b + (size_t)(wave * 64 + nt * 16 + l15) * 384 + quad * 8;
        }

        auto loadB = [&](bf16x8* b, int kk) {
            #pragma unroll
            for (int nt = 0; nt < 4; ++nt)
                b[nt] = *(const bf16x8*)(bp[nt] + kk);
        };
        auto loadA = [&](bf16x8* a, int kk) {
            int go = (((kk >> 3) + quad) ^ rx) << 4;
            #pragma unroll
            for (int mt = 0; mt < 4; ++mt)
                a[mt] = *(const bf16x8*)(Ab + abase + mt * 12288 + go);
        };
        auto mfmas = [&](bf16x8* a, bf16x8* b) {
            #pragma unroll
            for (int mt = 0; mt < 4; ++mt)
                #pragma unroll
                for (int nt = 0; nt < 4; ++nt)
                    acc[mt][nt] = __builtin_amdgcn_mfma_f32_16x16x32_bf16(
                        a[mt], b[nt], acc[mt][nt], 0, 0, 0);
        };

        // software pipeline: B prefetched one kstep ahead (global, ~200cyc L2)
        bf16x8 b0[4], b1f[4], a0[4], a1[4];
        loadB(b0, 0);
        #pragma unroll
        for (int kk = 0; kk < 384; kk += 64) {
            loadB(b1f, kk + 32);
            loadA(a0, kk);
            mfmas(a0, b0);
            if (kk + 64 < 384) loadB(b0, kk + 64);
            loadA(a1, kk + 32);
            mfmas(a1, b1f);
        }

        if (phase < 4) {
            // acc[mt][q][r] = gates[row = mt*16+quad*4+r][q*256 + j], j = phase*64+wave*16+l15
            int j = phase * 64 + wave * 16 + l15;
            float bq0 = b1[j], bq1 = b1[256 + j], bq2 = b1[512 + j], bq3 = b1[768 + j];
            int e = 128 + j, ge = e >> 3, oe = (e & 7) * 2;
            #pragma unroll
            for (int mt = 0; mt < 4; ++mt) {
                #pragma unroll
                for (int r = 0; r < 4; ++r) {
                    int rowl = mt * 16 + quad * 4 + r;
                    float hprev = bf2f(*(const unsigned short*)
                                       (Ab + lds_off(rowl, ge) + oe));
                    float hv  = ftanh(acc[mt][0][r] + bq0);
                    float igv = fsigmoid(acc[mt][1][r] + bq1);
                    float fgv = fsigmoid(acc[mt][2][r] + bq2);
                    float ogv = fsigmoid(acc[mt][3][r] + bq3);
                    out_nh[(r0 + rowl) * 256 + j] = ogv * ftanh(fgv * hprev + igv * hv);
                }
            }
        } else {
            // acc[mt][nt][r] = logits[row][col = wave*64 + nt*16 + l15]
            float bo[4];
            #pragma unroll
            for (int nt = 0; nt < 4; ++nt) bo[nt] = b2[wave * 64 + nt * 16 + l15];
            #pragma unroll
            for (int mt = 0; mt < 4; ++mt)
                #pragma unroll
                for (int nt = 0; nt < 4; ++nt)
                    #pragma unroll
                    for (int r = 0; r < 4; ++r)
                        acc[mt][nt][r] += bo[nt];

            float pm[4][4], ps[4][4];
            #pragma unroll
            for (int mt = 0; mt < 4; ++mt)
                #pragma unroll
                for (int r = 0; r < 4; ++r) {
                    float m = acc[mt][0][r];
                    #pragma unroll
                    for (int nt = 1; nt < 4; ++nt) m = fmaxf(m, acc[mt][nt][r]);
                    pm[mt][r] = m;
                }
            #pragma unroll
            for (int mask = 1; mask < 16; mask <<= 1)
                #pragma unroll
                for (int mt = 0; mt < 4; ++mt)
                    #pragma unroll
                    for (int r = 0; r < 4; ++r)
                        pm[mt][r] = fmaxf(pm[mt][r], __shfl_xor(pm[mt][r], mask, 64));
            #pragma unroll
            for (int mt = 0; mt < 4; ++mt)
                #pragma unroll
                for (int r = 0; r < 4; ++r) {
                    float s = 0.f;
                    #pragma unroll
                    for (int nt = 0; nt < 4; ++nt)
                        s += __expf(acc[mt][nt][r] - pm[mt][r]);
                    ps[mt][r] = s;
                }
            #pragma unroll
            for (int mask = 1; mask < 16; mask <<= 1)
                #pragma unroll
                for (int mt = 0; mt < 4; ++mt)
                    #pragma unroll
                    for (int r = 0; r < 4; ++r)
                        ps[mt][r] += __shfl_xor(ps[mt][r], mask, 64);

            if (l15 == 0) {
                #pragma unroll
                for (int mt = 0; mt < 4; ++mt)
                    #pragma unroll
                    for (int r = 0; r < 4; ++r) {
                        int rowl = mt * 16 + quad * 4 + r;
                        red_m[wave][rowl] = pm[mt][r];
                        red_s[wave][rowl] = ps[mt][r];
                    }
            }
            __syncthreads();
            #pragma unroll
            for (int mt = 0; mt < 4; ++mt)
                #pragma unroll
                for (int r = 0; r < 4; ++r) {
                    int rowl = mt * 16 + quad * 4 + r;
                    float M = red_m[0][rowl];
                    #pragma unroll
                    for (int w = 1; w < 4; ++w) M = fmaxf(M, red_m[w][rowl]);
                    float S = 0.f;
                    #pragma unroll
                    for (int w = 0; w < 4; ++w)
                        S += red_s[w][rowl] * __expf(red_m[w][rowl] - M);
                    float lz = M + logf(S);
                    #pragma unroll
                    for (int nt = 0; nt < 4; ++nt)
                        out_ls[(r0 + rowl) * 256 + wave * 64 + nt * 16 + l15] =
                            acc[mt][nt][r] - lz;
                }
        }
    }
}

extern "C" void kernel_launch(void* const* d_in, const int* in_sizes, int n_in,
                              void* d_out, int out_size, void* d_ws, size_t ws_size,
                              hipStream_t stream) {
    const float* input  = (const float*)d_in[0];
    const float* hidden = (const float*)d_in[1];
    const float* w1     = (const float*)d_in[2];
    const float* b1     = (const float*)d_in[3];
    const float* w2     = (const float*)d_in[4];
    const float* b2     = (const float*)d_in[5];
    float* out = (float*)d_out;
    unsigned short* wb = (unsigned short*)d_ws;   // needs 983040 B

    conv_w<<<dim3((NW1 + NW2) / 4 / 256), dim3(256), 0, stream>>>(w1, w2, wb);
    lstm_fused<<<dim3(65536 / BM), dim3(256), 0, stream>>>(
        input, hidden, wb, wb + NW1, b1, b2,
        out, out + (size_t)65536 * 256);
}